// Round 13
// baseline (1456.027 us; speedup 1.0000x reference)
//
#include <hip/hip_runtime.h>
#include <cstdint>
#include <cstddef>

#define TLEN 512
#define BATCH 1000
#define NEVS 102400   // events per source
#define HID 64
#define W0S 8         // fused0 steps per phase
#define NP (TLEN / W0S)

__device__ __forceinline__ float fast_rcp(float x) {
#if __has_builtin(__builtin_amdgcn_rcpf)
    return __builtin_amdgcn_rcpf(x);
#else
    return 1.0f / x;
#endif
}
__device__ __forceinline__ float sigm(float x) { return fast_rcp(1.0f + __expf(-x)); }
__device__ __forceinline__ float tanh_f(float x) { return fmaf(2.0f, sigm(2.0f * x), -1.0f); }

// Wave-wide sum broadcast (rocPRIM gfx9 DPP pattern).
__device__ __forceinline__ float wave_sum_bcast(float x) {
#if __has_builtin(__builtin_amdgcn_update_dpp) && __has_builtin(__builtin_amdgcn_readlane)
    x += __int_as_float(__builtin_amdgcn_update_dpp(0, __float_as_int(x), 0x111, 0xf, 0xf, true)); // row_shr:1
    x += __int_as_float(__builtin_amdgcn_update_dpp(0, __float_as_int(x), 0x112, 0xf, 0xf, true)); // row_shr:2
    x += __int_as_float(__builtin_amdgcn_update_dpp(0, __float_as_int(x), 0x114, 0xf, 0xf, true)); // row_shr:4
    x += __int_as_float(__builtin_amdgcn_update_dpp(0, __float_as_int(x), 0x118, 0xf, 0xf, true)); // row_shr:8
    x += __int_as_float(__builtin_amdgcn_update_dpp(0, __float_as_int(x), 0x142, 0xa, 0xf, true)); // row_bcast:15
    x += __int_as_float(__builtin_amdgcn_update_dpp(0, __float_as_int(x), 0x143, 0xc, 0xf, true)); // row_bcast:31
    return __int_as_float(__builtin_amdgcn_readlane(__float_as_int(x), 63));
#else
#pragma unroll
    for (int off = 1; off < 64; off <<= 1) x += __shfl_xor(x, off, 64);
    return x;
#endif
}

// Two independent wave sums, stages interleaved for ILP.
__device__ __forceinline__ void wave_sum2(float& a, float& b) {
#if __has_builtin(__builtin_amdgcn_update_dpp) && __has_builtin(__builtin_amdgcn_readlane)
    int ta, tb;
    ta = __builtin_amdgcn_update_dpp(0, __float_as_int(a), 0x111, 0xf, 0xf, true);
    tb = __builtin_amdgcn_update_dpp(0, __float_as_int(b), 0x111, 0xf, 0xf, true);
    a += __int_as_float(ta); b += __int_as_float(tb);
    ta = __builtin_amdgcn_update_dpp(0, __float_as_int(a), 0x112, 0xf, 0xf, true);
    tb = __builtin_amdgcn_update_dpp(0, __float_as_int(b), 0x112, 0xf, 0xf, true);
    a += __int_as_float(ta); b += __int_as_float(tb);
    ta = __builtin_amdgcn_update_dpp(0, __float_as_int(a), 0x114, 0xf, 0xf, true);
    tb = __builtin_amdgcn_update_dpp(0, __float_as_int(b), 0x114, 0xf, 0xf, true);
    a += __int_as_float(ta); b += __int_as_float(tb);
    ta = __builtin_amdgcn_update_dpp(0, __float_as_int(a), 0x118, 0xf, 0xf, true);
    tb = __builtin_amdgcn_update_dpp(0, __float_as_int(b), 0x118, 0xf, 0xf, true);
    a += __int_as_float(ta); b += __int_as_float(tb);
    ta = __builtin_amdgcn_update_dpp(0, __float_as_int(a), 0x142, 0xa, 0xf, true);
    tb = __builtin_amdgcn_update_dpp(0, __float_as_int(b), 0x142, 0xa, 0xf, true);
    a += __int_as_float(ta); b += __int_as_float(tb);
    ta = __builtin_amdgcn_update_dpp(0, __float_as_int(a), 0x143, 0xc, 0xf, true);
    tb = __builtin_amdgcn_update_dpp(0, __float_as_int(b), 0x143, 0xc, 0xf, true);
    a += __int_as_float(ta); b += __int_as_float(tb);
    a = __int_as_float(__builtin_amdgcn_readlane(__float_as_int(a), 63));
    b = __int_as_float(__builtin_amdgcn_readlane(__float_as_int(b), 63));
#else
    a = wave_sum_bcast(a); b = wave_sum_bcast(b);
#endif
}

// Broadcast lane idx (compile-time after unroll) of x0:x1 (lanes 0-63 : 64-127).
__device__ __forceinline__ float rlx(float x0, float x1, int idx) {
#if __has_builtin(__builtin_amdgcn_readlane)
    if (idx < 64) return __int_as_float(__builtin_amdgcn_readlane(__float_as_int(x0), idx));
    return __int_as_float(__builtin_amdgcn_readlane(__float_as_int(x1), idx - 64));
#else
    return (idx < 64) ? __shfl(x0, idx, 64) : __shfl(x1, idx - 64, 64);
#endif
}

// ===========================================================================
// map[b*512+t] = src<<20 | e  (sources partition the (b,t) grid: exactly one)
// ===========================================================================
__global__ __launch_bounds__(256) void map_build_kernel(
    const int* __restrict__ b0, const int* __restrict__ t0,
    const int* __restrict__ b1, const int* __restrict__ t1,
    const int* __restrict__ b2, const int* __restrict__ t2,
    const int* __restrict__ b3, const int* __restrict__ t3,
    const int* __restrict__ b4, const int* __restrict__ t4,
    int* __restrict__ map)
{
    const int src = blockIdx.y;
    const int* bi = src == 0 ? b0 : src == 1 ? b1 : src == 2 ? b2 : src == 3 ? b3 : b4;
    const int* ti = src == 0 ? t0 : src == 1 ? t1 : src == 2 ? t2 : src == 3 ? t3 : t4;
    const int e = blockIdx.x * 256 + threadIdx.x;
    map[bi[e] * TLEN + ti[e]] = (src << 20) | e;
}

// ===========================================================================
// Composed projection weights: wp[row][col], row=(src,j) [130], col=dir*256+r.
// row j<IND: W_src[j] . Wih0[col]; row j==IND: b_src . Wih0[col] + bih+bhh.
// ===========================================================================
__global__ __launch_bounds__(512) void compose_kernel(
    const float* __restrict__ W0, const float* __restrict__ B0,
    const float* __restrict__ W1, const float* __restrict__ B1,
    const float* __restrict__ W2, const float* __restrict__ B2,
    const float* __restrict__ W3, const float* __restrict__ B3,
    const float* __restrict__ W4, const float* __restrict__ B4,
    const float* __restrict__ Wih, const float* __restrict__ bih,
    const float* __restrict__ bhh, float* __restrict__ wp)
{
    const int col = threadIdx.x;   // 0..511 == dir*256 + r == Wih row index
    const int row = blockIdx.x;    // 0..129
    const float* srcW; const float* srcB; int base, IND;
    if (row < 9)        { srcW = W0; srcB = B0; base = 0;   IND = 8;  }
    else if (row < 27)  { srcW = W1; srcB = B1; base = 9;   IND = 17; }
    else if (row < 53)  { srcW = W2; srcB = B2; base = 27;  IND = 25; }
    else if (row < 120) { srcW = W3; srcB = B3; base = 53;  IND = 66; }
    else                { srcW = W4; srcB = B4; base = 120; IND = 9;  }
    const int j = row - base;
    const float* xrow = (j < IND) ? (srcW + (size_t)j * 64) : srcB;
    const float* wr = Wih + (size_t)col * 64;
    float acc = 0.0f;
#pragma unroll
    for (int h2 = 0; h2 < 64; ++h2) acc = fmaf(xrow[h2], wr[h2], acc);
    if (j == IND) acc += bih[col] + bhh[col];
    wp[(size_t)row * 512 + col] = acc;
}

// ===========================================================================
// dot4r: event x (in registers across the wave's lanes, broadcast via
// readlane) against LDS weights. Only w-reads touch LDS -> the per-event
// chain is w-b128 -> FMA(SGPR x), no x-broadcast LDS latency on the chain.
// Per-column accumulation order identical to r7's dot4 (bit-exact).
// ===========================================================================
template<int NB, int BASE>
__device__ __forceinline__ float4 dot4r(const float* wT, float x0, float x1, int colq) {
    float ax = 0.f, ay = 0.f, az = 0.f, aw = 0.f;
#pragma unroll
    for (int jb = 0; jb < NB; ++jb) {
        const float* w = wT + (size_t)(BASE + 4 * jb) * 256 + 4 * colq;
        const float4 w0 = *(const float4*)(w);
        const float4 w1 = *(const float4*)(w + 256);
        const float4 w2 = *(const float4*)(w + 512);
        const float4 w3 = *(const float4*)(w + 768);
        const float xs0 = rlx(x0, x1, 4 * jb + 0);
        const float xs1 = rlx(x0, x1, 4 * jb + 1);
        const float xs2 = rlx(x0, x1, 4 * jb + 2);
        const float xs3 = rlx(x0, x1, 4 * jb + 3);
        ax = fmaf(xs0, w0.x, ax); ay = fmaf(xs0, w0.y, ay);
        az = fmaf(xs0, w0.z, az); aw = fmaf(xs0, w0.w, aw);
        ax = fmaf(xs1, w1.x, ax); ay = fmaf(xs1, w1.y, ay);
        az = fmaf(xs1, w1.z, az); aw = fmaf(xs1, w1.w, aw);
        ax = fmaf(xs2, w2.x, ax); ay = fmaf(xs2, w2.y, ay);
        az = fmaf(xs2, w2.z, az); aw = fmaf(xs2, w2.w, aw);
        ax = fmaf(xs3, w3.x, ax); ay = fmaf(xs3, w3.y, ay);
        az = fmaf(xs3, w3.z, az); aw = fmaf(xs3, w3.w, aw);
    }
    return make_float4(ax, ay, az, aw);
}

// ===========================================================================
// Fused layer-0 v7 = r7 structure + x-in-registers (readlane broadcast) +
// consumer winP prefetch. Block = (b,dir), 576 threads: 8 producer waves
// (wave = event; gathers its own x into 1-2 VGPRs, dots it next phase) +
// 1 consumer wave. Pipeline: gather(p+2) || A1(p+1) || B(p).
// LDS: wT 135.2K + winP 16K = ~151.5 KB (1 block/CU). No xbuf/mcls.
// ===========================================================================
__global__ __launch_bounds__(576, 1) void fused0_kernel(
    const float* __restrict__ ccba_num,
    const float* __restrict__ cdtx_num, const int* __restrict__ cdtx_cat, const float* __restrict__ cdtx_tab,
    const float* __restrict__ cust_num, const int* __restrict__ cust_cat, const float* __restrict__ cust_tab,
    const float* __restrict__ dp_num,   const int* __restrict__ dp_cat,   const float* __restrict__ dp_tab,
    const float* __restrict__ remit_num, const int* __restrict__ remit_cat, const float* __restrict__ remit_tab,
    const float* __restrict__ wp, const int* __restrict__ map,
    const float* __restrict__ Whh, const float* __restrict__ Whr,
    float* __restrict__ h0)
{
    __shared__ float wT[132 * 256];          // [row][col], rows 130/131 zeroed
    __shared__ float winP[2][W0S][256];

    const int tid = threadIdx.x;
    const int b = blockIdx.x >> 1, dir = blockIdx.x & 1;

    // ---- stage weights: this dir's 256-col half of every row ----
    {
        const float4* wp4 = (const float4*)wp;   // 130 rows x 128 float4
        float4* wT4 = (float4*)wT;
        for (int i = tid; i < 130 * 64; i += 576) {
            const int row = i >> 6, c4 = i & 63;
            wT4[(row << 6) + c4] = wp4[(row << 7) + (dir << 6) + c4];
        }
        if (tid < 128) wT4[130 * 64 + tid] = make_float4(0.f, 0.f, 0.f, 0.f);
    }

    // ---- consumer state (wave 8) ----
    float whh4[4] = {0.f, 0.f, 0.f, 0.f};
    float whr = 0.f, h = 0.f, c = 0.f;
    float* h0p = h0 + (size_t)b * TLEN * 2 + dir;
    if (tid >= 512) {
        const int lane = tid - 512;
#pragma unroll
        for (int k = 0; k < 4; ++k) whh4[k] = Whh[dir * 256 + k * 64 + lane];
        whr = Whr[dir * HID + lane];
    }

    struct GX { float x0, x1; int mc; };

    // gather: wave = one event; lane v keeps padded-x value v IN REGISTER.
    auto g_load = [&](int P) -> GX {
        GX g; g.x0 = 0.f; g.x1 = 0.f;
        const int ev = tid >> 6, v = tid & 63;
        const int s = P * W0S + ev;
        const int t = dir ? (TLEN - 1 - s) : s;
        g.mc = map[b * TLEN + t];
        const int src = g.mc >> 20, e = g.mc & 0xFFFFF;
        switch (src) {
        case 0:
            if (v < 8) g.x0 = ccba_num[(size_t)e * 8 + v];
            else if (v == 8) g.x0 = 1.0f;
            break;
        case 1:
            if (v < 16) g.x0 = cdtx_tab[(size_t)cdtx_cat[e * 2 + (v >> 3)] * 8 + (v & 7)];
            else if (v == 16) g.x0 = cdtx_num[e];
            else if (v == 17) g.x0 = 1.0f;
            break;
        case 2:
            if (v < 24) g.x0 = cust_tab[(size_t)cust_cat[e * 3 + (v >> 3)] * 8 + (v & 7)];
            else if (v == 24) g.x0 = cust_num[e];
            else if (v == 25) g.x0 = 1.0f;
            break;
        case 3:
            g.x0 = dp_tab[(size_t)dp_cat[e * 8 + (v >> 3)] * 8 + (v & 7)];
            if (v < 2) g.x1 = dp_num[(size_t)e * 2 + v];
            else if (v == 2) g.x1 = 1.0f;
            break;
        default:
            if (v < 8) g.x0 = remit_tab[(size_t)remit_cat[e] * 8 + v];
            else if (v == 8) g.x0 = remit_num[e];
            else if (v == 9) g.x0 = 1.0f;
            break;
        }
        return g;
    };

    // A1: wave = its own event; src is wave-uniform (scalar branch).
    auto a1 = [&](const GX& g, int buf) {
        const int ev = tid >> 6, colq = tid & 63;
        const int src = __builtin_amdgcn_readfirstlane(g.mc) >> 20;
        float4 acc;
        switch (src) {
        case 0:  acc = dot4r<3, 0>(wT, g.x0, g.x1, colq);   break;
        case 1:  acc = dot4r<5, 9>(wT, g.x0, g.x1, colq);   break;
        case 2:  acc = dot4r<7, 27>(wT, g.x0, g.x1, colq);  break;
        case 3:  acc = dot4r<17, 53>(wT, g.x0, g.x1, colq); break;
        default: acc = dot4r<3, 120>(wT, g.x0, g.x1, colq); break;
        }
        ((float4*)winP[buf][ev])[colq] = acc;
    };

    // B: consumer wave runs W0S recurrence steps for phase P (1-step prefetch).
    auto bstep = [&](int P) {
        const int buf = P & 1;
        const int lane = tid - 512;
        float g0 = winP[buf][0][lane];
        float g1 = winP[buf][0][64 + lane];
        float g2 = winP[buf][0][128 + lane];
        float g3 = winP[buf][0][192 + lane];
        for (int sl = 0; sl < W0S; ++sl) {
            const int sn = (sl + 1 < W0S) ? sl + 1 : sl;
            const float n0 = winP[buf][sn][lane];
            const float n1 = winP[buf][sn][64 + lane];
            const float n2 = winP[buf][sn][128 + lane];
            const float n3 = winP[buf][sn][192 + lane];
            const float gi = fmaf(whh4[0], h, g0);
            const float gf = fmaf(whh4[1], h, g1);
            const float gg = fmaf(whh4[2], h, g2);
            const float go = fmaf(whh4[3], h, g3);
            c = sigm(gf) * c + sigm(gi) * tanh_f(gg);
            h = wave_sum_bcast(sigm(go) * tanh_f(c) * whr);
            const int s = P * W0S + sl;
            const int tt = dir ? (TLEN - 1 - s) : s;
            if (lane == 0) h0p[(size_t)tt * 2] = h;
            g0 = n0; g1 = n1; g2 = n2; g3 = n3;
        }
    };

    // ---- prologue ----
    GX xc{};
    if (tid < 512) xc = g_load(0);
    __syncthreads();                       // wT staged
    if (tid < 512) {
        GX xn = g_load(1);
        a1(xc, 0);                         // winP[0] <- phase 0 gates
        xc = xn;
    }
    __syncthreads();                       // winP[0] ready

    // ---- main loop: gather(p+2) || A1(p+1) || B(p) ----
    for (int p = 0; p < NP; ++p) {
        if (tid < 512) {
            GX gg{};
            const bool hg = (p + 2 < NP);
            if (hg) gg = g_load(p + 2);
            if (p + 1 < NP) a1(xc, (p + 1) & 1);
            if (hg) xc = gg;
        } else if (tid < 576) {
            bstep(p);
        }
        __syncthreads();
    }
}

// ===========================================================================
// LSTM layer 1 (insz=2): one wave per b, BOTH dirs as two interleaved chains;
// x staged in LDS (r12-measured improvement). Volatile weight loads.
// ===========================================================================
__global__ __launch_bounds__(256, 2) void lstm1_kernel(
    const float* __restrict__ h0, const float* __restrict__ Wih,
    const float* __restrict__ Whh, const float* __restrict__ Whr,
    const float* __restrict__ bih, const float* __restrict__ bhh,
    float* __restrict__ h1)
{
    __shared__ float2 xsh[4][TLEN];
    const int w = threadIdx.x >> 6, lane = threadIdx.x & 63;
    const int b0 = blockIdx.x * 4;
    const int b = b0 + w;                      // grid 250 -> b 0..999

    {
        const float2* src = (const float2*)(h0 + (size_t)b0 * TLEN * 2);
        for (int i = threadIdx.x; i < 4 * TLEN; i += 256)
            xsh[i >> 9][i & 511] = src[i];
    }

    const volatile float* vWih = Wih;
    const volatile float* vWhh = Whh;
    const volatile float* vWhr = Whr;
    const volatile float* vbih = bih;
    const volatile float* vbhh = bhh;

    float wi0[2][4], wi1[2][4], whh[2][4], bias[2][4], whr[2];
#pragma unroll
    for (int d = 0; d < 2; ++d) {
#pragma unroll
        for (int k = 0; k < 4; ++k) {
            const int r = d * 256 + k * 64 + lane;
            wi0[d][k] = vWih[(size_t)r * 2 + 0];
            wi1[d][k] = vWih[(size_t)r * 2 + 1];
            whh[d][k] = vWhh[r];
            bias[d][k] = vbih[r] + vbhh[r];
        }
        whr[d] = vWhr[d * HID + lane];
    }
    __syncthreads();

    float hA = 0, cA = 0, hB = 0, cB = 0;
    const float2* hb = xsh[w];

    float2 xA = hb[0];            // fwd t=0
    float2 xB = hb[TLEN - 1];     // bwd t=511
    for (int t = 0; t < TLEN; ++t) {
        const int tn = (t + 1 < TLEN) ? t + 1 : t;
        const float2 xAn = hb[tn];
        const float2 xBn = hb[TLEN - 1 - tn];
        float gA[4], gB[4];
#pragma unroll
        for (int k = 0; k < 4; ++k) {
            gA[k] = fmaf(whh[0][k], hA, fmaf(wi1[0][k], xA.y, fmaf(wi0[0][k], xA.x, bias[0][k])));
            gB[k] = fmaf(whh[1][k], hB, fmaf(wi1[1][k], xB.y, fmaf(wi0[1][k], xB.x, bias[1][k])));
        }
        cA = sigm(gA[1]) * cA + sigm(gA[0]) * tanh_f(gA[2]);
        cB = sigm(gB[1]) * cB + sigm(gB[0]) * tanh_f(gB[2]);
        float pA = sigm(gA[3]) * tanh_f(cA) * whr[0];
        float pB = sigm(gB[3]) * tanh_f(cB) * whr[1];
        wave_sum2(pA, pB);
        hA = pA; hB = pB;
        if (lane == 0) {
            h1[((size_t)b * TLEN + t) * 2 + 0] = hA;
            h1[((size_t)b * TLEN + (TLEN - 1 - t)) * 2 + 1] = hB;
        }
        xA = xAn; xB = xBn;
    }
}

__global__ __launch_bounds__(256) void mean_kernel(
    const float2* __restrict__ h1, float* __restrict__ out)
{
    int i = blockIdx.x * 256 + threadIdx.x;
    if (i < BATCH * TLEN) {
        float2 v = h1[i];
        out[i] = 0.5f * (v.x + v.y);
    }
}

// ===========================================================================
extern "C" void kernel_launch(void* const* d_in, const int* in_sizes, int n_in,
                              void* d_out, int out_size, void* d_ws, size_t ws_size,
                              hipStream_t stream)
{
    const float* ccba_num = (const float*)d_in[0];
    const int*   ccba_bi  = (const int*)d_in[1];
    const int*   ccba_ti  = (const int*)d_in[2];
    const float* ccba_W   = (const float*)d_in[3];
    const float* ccba_b   = (const float*)d_in[4];
    const float* cdtx_num = (const float*)d_in[5];
    const int*   cdtx_cat = (const int*)d_in[6];
    const float* cdtx_tab = (const float*)d_in[7];
    const int*   cdtx_bi  = (const int*)d_in[8];
    const int*   cdtx_ti  = (const int*)d_in[9];
    const float* cdtx_W   = (const float*)d_in[10];
    const float* cdtx_b   = (const float*)d_in[11];
    const float* cust_num = (const float*)d_in[12];
    const int*   cust_cat = (const int*)d_in[13];
    const float* cust_tab = (const float*)d_in[14];
    const int*   cust_bi  = (const int*)d_in[15];
    const int*   cust_ti  = (const int*)d_in[16];
    const float* cust_W   = (const float*)d_in[17];
    const float* cust_b   = (const float*)d_in[18];
    const float* dp_num   = (const float*)d_in[19];
    const int*   dp_cat   = (const int*)d_in[20];
    const float* dp_tab   = (const float*)d_in[21];
    const int*   dp_bi    = (const int*)d_in[22];
    const int*   dp_ti    = (const int*)d_in[23];
    const float* dp_W     = (const float*)d_in[24];
    const float* dp_b     = (const float*)d_in[25];
    const float* remit_num = (const float*)d_in[26];
    const int*   remit_cat = (const int*)d_in[27];
    const float* remit_tab = (const float*)d_in[28];
    const int*   remit_bi  = (const int*)d_in[29];
    const int*   remit_ti  = (const int*)d_in[30];
    const float* remit_W   = (const float*)d_in[31];
    const float* remit_b   = (const float*)d_in[32];
    const float* Wih0 = (const float*)d_in[33];
    const float* Whh0 = (const float*)d_in[34];
    const float* Whr0 = (const float*)d_in[35];
    const float* bih0 = (const float*)d_in[36];
    const float* bhh0 = (const float*)d_in[37];
    const float* Wih1 = (const float*)d_in[38];
    const float* Whh1 = (const float*)d_in[39];
    const float* Whr1 = (const float*)d_in[40];
    const float* bih1 = (const float*)d_in[41];
    const float* bhh1 = (const float*)d_in[42];

    float* out = (float*)d_out;

    // Workspace: wp (266,240) | map (2,048,000) | h0 (4,096,000) | h1 (4,096,000)
    char* ws = (char*)d_ws;
    float* wp  = (float*)ws;
    int*   map = (int*)  (ws + 266240ull);
    float* h0  = (float*)(ws + 266240ull + 2048000ull);
    float* h1  = (float*)(ws + 266240ull + 2048000ull + 4096000ull);

    compose_kernel<<<130, 512, 0, stream>>>(
        ccba_W, ccba_b, cdtx_W, cdtx_b, cust_W, cust_b,
        dp_W, dp_b, remit_W, remit_b, Wih0, bih0, bhh0, wp);

    map_build_kernel<<<dim3(NEVS / 256, 5), 256, 0, stream>>>(
        ccba_bi, ccba_ti, cdtx_bi, cdtx_ti, cust_bi, cust_ti,
        dp_bi, dp_ti, remit_bi, remit_ti, map);

    fused0_kernel<<<2 * BATCH, 576, 0, stream>>>(
        ccba_num,
        cdtx_num, cdtx_cat, cdtx_tab,
        cust_num, cust_cat, cust_tab,
        dp_num, dp_cat, dp_tab,
        remit_num, remit_cat, remit_tab,
        wp, map, Whh0, Whr0, h0);

    lstm1_kernel<<<250, 256, 0, stream>>>(h0, Wih1, Whh1, Whr1, bih1, bhh1, h1);
    mean_kernel<<<(BATCH * TLEN + 255) / 256, 256, 0, stream>>>((const float2*)h1, out);
}

// Round 14
// 1316.233 us; speedup vs baseline: 1.1062x; 1.1062x over previous
//
#include <hip/hip_runtime.h>
#include <cstdint>
#include <cstddef>

#define TLEN 512
#define BATCH 1000
#define NEVS 102400   // events per source
#define HID 64

__device__ __forceinline__ float fast_rcp(float x) {
#if __has_builtin(__builtin_amdgcn_rcpf)
    return __builtin_amdgcn_rcpf(x);
#else
    return 1.0f / x;
#endif
}
__device__ __forceinline__ float sigm(float x) { return fast_rcp(1.0f + __expf(-x)); }
__device__ __forceinline__ float tanh_f(float x) { return fmaf(2.0f, sigm(2.0f * x), -1.0f); }

// Wave-wide sum broadcast (rocPRIM gfx9 DPP pattern).
__device__ __forceinline__ float wave_sum_bcast(float x) {
#if __has_builtin(__builtin_amdgcn_update_dpp) && __has_builtin(__builtin_amdgcn_readlane)
    x += __int_as_float(__builtin_amdgcn_update_dpp(0, __float_as_int(x), 0x111, 0xf, 0xf, true)); // row_shr:1
    x += __int_as_float(__builtin_amdgcn_update_dpp(0, __float_as_int(x), 0x112, 0xf, 0xf, true)); // row_shr:2
    x += __int_as_float(__builtin_amdgcn_update_dpp(0, __float_as_int(x), 0x114, 0xf, 0xf, true)); // row_shr:4
    x += __int_as_float(__builtin_amdgcn_update_dpp(0, __float_as_int(x), 0x118, 0xf, 0xf, true)); // row_shr:8
    x += __int_as_float(__builtin_amdgcn_update_dpp(0, __float_as_int(x), 0x142, 0xa, 0xf, true)); // row_bcast:15
    x += __int_as_float(__builtin_amdgcn_update_dpp(0, __float_as_int(x), 0x143, 0xc, 0xf, true)); // row_bcast:31
    return __int_as_float(__builtin_amdgcn_readlane(__float_as_int(x), 63));
#else
#pragma unroll
    for (int off = 1; off < 64; off <<= 1) x += __shfl_xor(x, off, 64);
    return x;
#endif
}

// Two independent wave sums, stages interleaved for ILP.
__device__ __forceinline__ void wave_sum2(float& a, float& b) {
#if __has_builtin(__builtin_amdgcn_update_dpp) && __has_builtin(__builtin_amdgcn_readlane)
    int ta, tb;
    ta = __builtin_amdgcn_update_dpp(0, __float_as_int(a), 0x111, 0xf, 0xf, true);
    tb = __builtin_amdgcn_update_dpp(0, __float_as_int(b), 0x111, 0xf, 0xf, true);
    a += __int_as_float(ta); b += __int_as_float(tb);
    ta = __builtin_amdgcn_update_dpp(0, __float_as_int(a), 0x112, 0xf, 0xf, true);
    tb = __builtin_amdgcn_update_dpp(0, __float_as_int(b), 0x112, 0xf, 0xf, true);
    a += __int_as_float(ta); b += __int_as_float(tb);
    ta = __builtin_amdgcn_update_dpp(0, __float_as_int(a), 0x114, 0xf, 0xf, true);
    tb = __builtin_amdgcn_update_dpp(0, __float_as_int(b), 0x114, 0xf, 0xf, true);
    a += __int_as_float(ta); b += __int_as_float(tb);
    ta = __builtin_amdgcn_update_dpp(0, __float_as_int(a), 0x118, 0xf, 0xf, true);
    tb = __builtin_amdgcn_update_dpp(0, __float_as_int(b), 0x118, 0xf, 0xf, true);
    a += __int_as_float(ta); b += __int_as_float(tb);
    ta = __builtin_amdgcn_update_dpp(0, __float_as_int(a), 0x142, 0xa, 0xf, true);
    tb = __builtin_amdgcn_update_dpp(0, __float_as_int(b), 0x142, 0xa, 0xf, true);
    a += __int_as_float(ta); b += __int_as_float(tb);
    ta = __builtin_amdgcn_update_dpp(0, __float_as_int(a), 0x143, 0xc, 0xf, true);
    tb = __builtin_amdgcn_update_dpp(0, __float_as_int(b), 0x143, 0xc, 0xf, true);
    a += __int_as_float(ta); b += __int_as_float(tb);
    a = __int_as_float(__builtin_amdgcn_readlane(__float_as_int(a), 63));
    b = __int_as_float(__builtin_amdgcn_readlane(__float_as_int(b), 63));
#else
    a = wave_sum_bcast(a); b = wave_sum_bcast(b);
#endif
}

// ===========================================================================
// map[b*512+t] = src<<20 | e  (sources partition the (b,t) grid: exactly one)
// ===========================================================================
__global__ __launch_bounds__(256) void map_build_kernel(
    const int* __restrict__ b0, const int* __restrict__ t0,
    const int* __restrict__ b1, const int* __restrict__ t1,
    const int* __restrict__ b2, const int* __restrict__ t2,
    const int* __restrict__ b3, const int* __restrict__ t3,
    const int* __restrict__ b4, const int* __restrict__ t4,
    int* __restrict__ map)
{
    const int src = blockIdx.y;
    const int* bi = src == 0 ? b0 : src == 1 ? b1 : src == 2 ? b2 : src == 3 ? b3 : b4;
    const int* ti = src == 0 ? t0 : src == 1 ? t1 : src == 2 ? t2 : src == 3 ? t3 : t4;
    const int e = blockIdx.x * 256 + threadIdx.x;
    map[bi[e] * TLEN + ti[e]] = (src << 20) | e;
}

// ===========================================================================
// Composed projection weights: wp[row][col], row=(src,j) [130], col=dir*256+r.
// row j<IND: W_src[j] . Wih0[col]; row j==IND: b_src . Wih0[col] + bih+bhh.
// ===========================================================================
__global__ __launch_bounds__(512) void compose_kernel(
    const float* __restrict__ W0, const float* __restrict__ B0,
    const float* __restrict__ W1, const float* __restrict__ B1,
    const float* __restrict__ W2, const float* __restrict__ B2,
    const float* __restrict__ W3, const float* __restrict__ B3,
    const float* __restrict__ W4, const float* __restrict__ B4,
    const float* __restrict__ Wih, const float* __restrict__ bih,
    const float* __restrict__ bhh, float* __restrict__ wp)
{
    const int col = threadIdx.x;   // 0..511 == dir*256 + r == Wih row index
    const int row = blockIdx.x;    // 0..129
    const float* srcW; const float* srcB; int base, IND;
    if (row < 9)        { srcW = W0; srcB = B0; base = 0;   IND = 8;  }
    else if (row < 27)  { srcW = W1; srcB = B1; base = 9;   IND = 17; }
    else if (row < 53)  { srcW = W2; srcB = B2; base = 27;  IND = 25; }
    else if (row < 120) { srcW = W3; srcB = B3; base = 53;  IND = 66; }
    else                { srcW = W4; srcB = B4; base = 120; IND = 9;  }
    const int j = row - base;
    const float* xrow = (j < IND) ? (srcW + (size_t)j * 64) : srcB;
    const float* wr = Wih + (size_t)col * 64;
    float acc = 0.0f;
#pragma unroll
    for (int h2 = 0; h2 < 64; ++h2) acc = fmaf(xrow[h2], wr[h2], acc);
    if (j == IND) acc += bih[col] + bhh[col];
    wp[(size_t)row * 512 + col] = acc;
}

// ===========================================================================
// dot4 (r7-proven, bit-exact): event x in LDS (broadcast reads) against
// LDS-resident weights; w reads are contiguous b128 (conflict-free).
// ===========================================================================
template<int NB, int BASE>
__device__ __forceinline__ float4 dot4(const float* wT, const float* xb, int colq) {
    float ax = 0.f, ay = 0.f, az = 0.f, aw = 0.f;
#pragma unroll
    for (int jb = 0; jb < NB; ++jb) {
        const float4 x4 = *(const float4*)(xb + 4 * jb);
        const float* w = wT + (size_t)(BASE + 4 * jb) * 256 + 4 * colq;
        const float4 w0 = *(const float4*)(w);
        const float4 w1 = *(const float4*)(w + 256);
        const float4 w2 = *(const float4*)(w + 512);
        const float4 w3 = *(const float4*)(w + 768);
        ax = fmaf(x4.x, w0.x, ax); ay = fmaf(x4.x, w0.y, ay);
        az = fmaf(x4.x, w0.z, az); aw = fmaf(x4.x, w0.w, aw);
        ax = fmaf(x4.y, w1.x, ax); ay = fmaf(x4.y, w1.y, ay);
        az = fmaf(x4.y, w1.z, az); aw = fmaf(x4.y, w1.w, aw);
        ax = fmaf(x4.z, w2.x, ax); ay = fmaf(x4.z, w2.y, ay);
        az = fmaf(x4.z, w2.z, az); aw = fmaf(x4.z, w2.w, aw);
        ax = fmaf(x4.w, w3.x, ax); ay = fmaf(x4.w, w3.y, ay);
        az = fmaf(x4.w, w3.z, az); aw = fmaf(x4.w, w3.w, aw);
    }
    return make_float4(ax, ay, az, aw);
}

// ===========================================================================
// Projection, BARRIER-FREE (the one untested axis): block = (b-group of 4,
// dir); 8 waves run free after wT staging. Wave = one event at a time:
// per-lane gather (b-localized -> clean FETCH, r7-proven) -> wave-private
// xbuf slot -> dot4 vs LDS wT -> contiguous 1KB row store into the
// L3-resident chunk buffer. 1-deep pipeline: next gather issued under dot.
// LDS: wT 135.2K + xbuf 4.4K = 139.5 KB (1 block/CU). ZERO loop barriers.
// ===========================================================================
__global__ __launch_bounds__(512, 1) void project_kernel(
    const float* __restrict__ ccba_num,
    const float* __restrict__ cdtx_num, const int* __restrict__ cdtx_cat, const float* __restrict__ cdtx_tab,
    const float* __restrict__ cust_num, const int* __restrict__ cust_cat, const float* __restrict__ cust_tab,
    const float* __restrict__ dp_num,   const int* __restrict__ dp_cat,   const float* __restrict__ dp_tab,
    const float* __restrict__ remit_num, const int* __restrict__ remit_cat, const float* __restrict__ remit_tab,
    const float* __restrict__ wp, const int* __restrict__ map,
    float* __restrict__ gf, float* __restrict__ gb,
    int f0, int len, int tcm)
{
    __shared__ float wT[132 * 256];      // [row][col-of-dir]; rows 130/131 = 0
    __shared__ float xbuf[8][2][68];     // wave-private, double-buffered

    const int tid = threadIdx.x;
    const int wv = tid >> 6, lane = tid & 63;
    const int bg = blockIdx.x, dir = blockIdx.y;
    float* gdst = dir ? gb : gf;

    // ---- stage weights: this dir's 256-col half of every row ----
    {
        const float4* wp4 = (const float4*)wp;   // 130 rows x 128 float4
        float4* wT4 = (float4*)wT;
        for (int i = tid; i < 130 * 64; i += 512) {
            const int row = i >> 6, c4 = i & 63;
            wT4[(row << 6) + c4] = wp4[(row << 7) + (dir << 6) + c4];
        }
        if (tid < 128) wT4[130 * 64 + tid] = make_float4(0.f, 0.f, 0.f, 0.f);
    }
    __syncthreads();   // the ONLY barrier

    struct GX { float x0, x1; int mc; };

    // gather one event's padded x: lane v holds value v (r7-proven pattern).
    auto g_load = [&](int bl, int lt) -> GX {
        GX g; g.x0 = 0.f; g.x1 = 0.f;
        const int b = bg * 4 + bl;
        const int t = dir ? (TLEN - 1 - f0 - lt) : (f0 + lt);
        g.mc = map[b * TLEN + t];
        const int src = g.mc >> 20, e = g.mc & 0xFFFFF;
        const int v = lane;
        switch (src) {
        case 0:
            if (v < 8) g.x0 = ccba_num[(size_t)e * 8 + v];
            else if (v == 8) g.x0 = 1.0f;
            break;
        case 1:
            if (v < 16) g.x0 = cdtx_tab[(size_t)cdtx_cat[e * 2 + (v >> 3)] * 8 + (v & 7)];
            else if (v == 16) g.x0 = cdtx_num[e];
            else if (v == 17) g.x0 = 1.0f;
            break;
        case 2:
            if (v < 24) g.x0 = cust_tab[(size_t)cust_cat[e * 3 + (v >> 3)] * 8 + (v & 7)];
            else if (v == 24) g.x0 = cust_num[e];
            else if (v == 25) g.x0 = 1.0f;
            break;
        case 3:
            g.x0 = dp_tab[(size_t)dp_cat[e * 8 + (v >> 3)] * 8 + (v & 7)];
            if (v < 2) g.x1 = dp_num[(size_t)e * 2 + v];
            else if (v == 2) g.x1 = 1.0f;
            break;
        default:
            if (v < 8) g.x0 = remit_tab[(size_t)remit_cat[e] * 8 + v];
            else if (v == 8) g.x0 = remit_num[e];
            else if (v == 9) g.x0 = 1.0f;
            break;
        }
        return g;
    };

    // wave wv handles events (bl, lt) with lt in {wv, wv+8, ...}, bl = 0..3
    int bl = 0, lt = wv, buf = 0;
    GX cur = g_load(bl, lt);
    while (bl < 4) {
        int nbl = bl, nlt = lt + 8;
        if (nlt >= len) { nbl = bl + 1; nlt = wv; }

        xbuf[wv][buf][lane] = cur.x0;
        if (lane < 4) xbuf[wv][buf][64 + lane] = cur.x1;

        GX nxt{};
        if (nbl < 4) nxt = g_load(nbl, nlt);   // HBM/L2 latency hides under dot

        const int src = __builtin_amdgcn_readfirstlane(cur.mc) >> 20;
        const float* xb = xbuf[wv][buf];
        float4 acc;
        switch (src) {
        case 0:  acc = dot4<3, 0>(wT, xb, lane);   break;
        case 1:  acc = dot4<5, 9>(wT, xb, lane);   break;
        case 2:  acc = dot4<7, 27>(wT, xb, lane);  break;
        case 3:  acc = dot4<17, 53>(wT, xb, lane); break;
        default: acc = dot4<3, 120>(wT, xb, lane); break;
        }
        const int b = bg * 4 + bl;
        *(float4*)&gdst[((size_t)(b * tcm + lt)) * 256 + 4 * lane] = acc;

        bl = nbl; lt = nlt; cur = nxt; buf ^= 1;
    }
}

// ===========================================================================
// Layer-0 recurrence over the chunk (r2-proven): one wave per (b,dir);
// 2000 concurrent chains; 2-step gate prefetch; (h,c) carried across chunks.
// ===========================================================================
__global__ __launch_bounds__(256) void rec_chunk_kernel(
    const float* __restrict__ gf, const float* __restrict__ gb,
    const float* __restrict__ Whh, const float* __restrict__ Whr,
    float* __restrict__ h0, float* __restrict__ hs, float* __restrict__ cs,
    int f0, int len, int tcm, int first)
{
    const int wv = threadIdx.x >> 6, lane = threadIdx.x & 63;
    const int p = blockIdx.x * 4 + wv;          // 0..1999
    const int b = p >> 1, dir = p & 1;

    float whh4[4];
#pragma unroll
    for (int k = 0; k < 4; ++k) whh4[k] = Whh[dir * 256 + k * 64 + lane];
    const float whr = Whr[dir * HID + lane];

    const float* g = (dir ? gb : gf) + (size_t)b * tcm * 256 + lane;
    float* h0p = h0 + (size_t)b * TLEN * 2 + dir;

    float h, c;
    if (first) { h = 0.0f; c = 0.0f; }
    else       { h = hs[p]; c = cs[(size_t)p * 64 + lane]; }

    auto ga = [&](int s) -> const float* {
        const int sc = (s < len) ? s : (len - 1);   // clamp; value unused past end
        return g + (size_t)sc * 256;
    };
    auto do_step = [&](const float (&G)[4], int s) {
        const float gi = fmaf(whh4[0], h, G[0]);
        const float gfv = fmaf(whh4[1], h, G[1]);
        const float gg = fmaf(whh4[2], h, G[2]);
        const float go = fmaf(whh4[3], h, G[3]);
        c = sigm(gfv) * c + sigm(gi) * tanh_f(gg);
        h = wave_sum_bcast(sigm(go) * tanh_f(c) * whr);
        const int t_out = dir ? (TLEN - 1 - f0 - s) : (f0 + s);
        if (lane == 0) h0p[(size_t)t_out * 2] = h;
    };

    float A[4], B[4];
    {
        const float* pa = ga(0); const float* pb = ga(1);
#pragma unroll
        for (int k = 0; k < 4; ++k) { A[k] = pa[k * 64]; B[k] = pb[k * 64]; }
    }
    for (int s = 0; s < len; s += 2) {
        float C[4], D[4];
        const float* pc = ga(s + 2); const float* pd = ga(s + 3);
#pragma unroll
        for (int k = 0; k < 4; ++k) { C[k] = pc[k * 64]; D[k] = pd[k * 64]; }
        do_step(A, s);
        if (s + 1 < len) do_step(B, s + 1);
#pragma unroll
        for (int k = 0; k < 4; ++k) { A[k] = C[k]; B[k] = D[k]; }
    }
    if (lane == 0) hs[p] = h;
    cs[(size_t)p * 64 + lane] = c;
}

// ===========================================================================
// LSTM layer 1 (insz=2): one wave per b, BOTH dirs as two interleaved chains;
// x staged in LDS (r12-measured -35 us). Volatile weight loads.
// ===========================================================================
__global__ __launch_bounds__(256, 2) void lstm1_kernel(
    const float* __restrict__ h0, const float* __restrict__ Wih,
    const float* __restrict__ Whh, const float* __restrict__ Whr,
    const float* __restrict__ bih, const float* __restrict__ bhh,
    float* __restrict__ h1)
{
    __shared__ float2 xsh[4][TLEN];
    const int w = threadIdx.x >> 6, lane = threadIdx.x & 63;
    const int b0 = blockIdx.x * 4;
    const int b = b0 + w;                      // grid 250 -> b 0..999

    {
        const float2* src = (const float2*)(h0 + (size_t)b0 * TLEN * 2);
        for (int i = threadIdx.x; i < 4 * TLEN; i += 256)
            xsh[i >> 9][i & 511] = src[i];
    }

    const volatile float* vWih = Wih;
    const volatile float* vWhh = Whh;
    const volatile float* vWhr = Whr;
    const volatile float* vbih = bih;
    const volatile float* vbhh = bhh;

    float wi0[2][4], wi1[2][4], whh[2][4], bias[2][4], whr[2];
#pragma unroll
    for (int d = 0; d < 2; ++d) {
#pragma unroll
        for (int k = 0; k < 4; ++k) {
            const int r = d * 256 + k * 64 + lane;
            wi0[d][k] = vWih[(size_t)r * 2 + 0];
            wi1[d][k] = vWih[(size_t)r * 2 + 1];
            whh[d][k] = vWhh[r];
            bias[d][k] = vbih[r] + vbhh[r];
        }
        whr[d] = vWhr[d * HID + lane];
    }
    __syncthreads();

    float hA = 0, cA = 0, hB = 0, cB = 0;
    const float2* hb = xsh[w];

    float2 xA = hb[0];            // fwd t=0
    float2 xB = hb[TLEN - 1];     // bwd t=511
    for (int t = 0; t < TLEN; ++t) {
        const int tn = (t + 1 < TLEN) ? t + 1 : t;
        const float2 xAn = hb[tn];
        const float2 xBn = hb[TLEN - 1 - tn];
        float gA[4], gB[4];
#pragma unroll
        for (int k = 0; k < 4; ++k) {
            gA[k] = fmaf(whh[0][k], hA, fmaf(wi1[0][k], xA.y, fmaf(wi0[0][k], xA.x, bias[0][k])));
            gB[k] = fmaf(whh[1][k], hB, fmaf(wi1[1][k], xB.y, fmaf(wi0[1][k], xB.x, bias[1][k])));
        }
        cA = sigm(gA[1]) * cA + sigm(gA[0]) * tanh_f(gA[2]);
        cB = sigm(gB[1]) * cB + sigm(gB[0]) * tanh_f(gB[2]);
        float pA = sigm(gA[3]) * tanh_f(cA) * whr[0];
        float pB = sigm(gB[3]) * tanh_f(cB) * whr[1];
        wave_sum2(pA, pB);
        hA = pA; hB = pB;
        if (lane == 0) {
            h1[((size_t)b * TLEN + t) * 2 + 0] = hA;
            h1[((size_t)b * TLEN + (TLEN - 1 - t)) * 2 + 1] = hB;
        }
        xA = xAn; xB = xBn;
    }
}

__global__ __launch_bounds__(256) void mean_kernel(
    const float2* __restrict__ h1, float* __restrict__ out)
{
    int i = blockIdx.x * 256 + threadIdx.x;
    if (i < BATCH * TLEN) {
        float2 v = h1[i];
        out[i] = 0.5f * (v.x + v.y);
    }
}

// ===========================================================================
extern "C" void kernel_launch(void* const* d_in, const int* in_sizes, int n_in,
                              void* d_out, int out_size, void* d_ws, size_t ws_size,
                              hipStream_t stream)
{
    const float* ccba_num = (const float*)d_in[0];
    const int*   ccba_bi  = (const int*)d_in[1];
    const int*   ccba_ti  = (const int*)d_in[2];
    const float* ccba_W   = (const float*)d_in[3];
    const float* ccba_b   = (const float*)d_in[4];
    const float* cdtx_num = (const float*)d_in[5];
    const int*   cdtx_cat = (const int*)d_in[6];
    const float* cdtx_tab = (const float*)d_in[7];
    const int*   cdtx_bi  = (const int*)d_in[8];
    const int*   cdtx_ti  = (const int*)d_in[9];
    const float* cdtx_W   = (const float*)d_in[10];
    const float* cdtx_b   = (const float*)d_in[11];
    const float* cust_num = (const float*)d_in[12];
    const int*   cust_cat = (const int*)d_in[13];
    const float* cust_tab = (const float*)d_in[14];
    const int*   cust_bi  = (const int*)d_in[15];
    const int*   cust_ti  = (const int*)d_in[16];
    const float* cust_W   = (const float*)d_in[17];
    const float* cust_b   = (const float*)d_in[18];
    const float* dp_num   = (const float*)d_in[19];
    const int*   dp_cat   = (const int*)d_in[20];
    const float* dp_tab   = (const float*)d_in[21];
    const int*   dp_bi    = (const int*)d_in[22];
    const int*   dp_ti    = (const int*)d_in[23];
    const float* dp_W     = (const float*)d_in[24];
    const float* dp_b     = (const float*)d_in[25];
    const float* remit_num = (const float*)d_in[26];
    const int*   remit_cat = (const int*)d_in[27];
    const float* remit_tab = (const float*)d_in[28];
    const int*   remit_bi  = (const int*)d_in[29];
    const int*   remit_ti  = (const int*)d_in[30];
    const float* remit_W   = (const float*)d_in[31];
    const float* remit_b   = (const float*)d_in[32];
    const float* Wih0 = (const float*)d_in[33];
    const float* Whh0 = (const float*)d_in[34];
    const float* Whr0 = (const float*)d_in[35];
    const float* bih0 = (const float*)d_in[36];
    const float* bhh0 = (const float*)d_in[37];
    const float* Wih1 = (const float*)d_in[38];
    const float* Whh1 = (const float*)d_in[39];
    const float* Whr1 = (const float*)d_in[40];
    const float* bih1 = (const float*)d_in[41];
    const float* bhh1 = (const float*)d_in[42];

    float* out = (float*)d_out;

    // Workspace: gf, gb (tcm * 1.024 MB each, [b][lt][256] layout) + fixed:
    //   h0 4,096,000 | h1 4,096,000 | wp 266,240 | hs 8,000 | cs 512,000
    //   map 2,048,000
    const size_t FIXED = 4096000ull + 4096000ull + 266240ull + 8000ull
                       + 512000ull + 2048000ull;
    size_t avail = (ws_size > FIXED) ? (ws_size - FIXED) : 0;
    int tcm = (int)(avail / 2048000ull);
    if (tcm < 1) tcm = 1;
    if (tcm > 86) tcm = 86;          // gf+gb <= 176 MB -> L3-resident
    if (tcm >= 2) tcm &= ~1;

    char* ws = (char*)d_ws;
    const size_t gfB = (size_t)tcm * 1024000ull;
    float* gf    = (float*)ws;
    float* gb    = (float*)(ws + gfB);
    char*  fixed = ws + 2 * gfB;
    float* h0    = (float*)fixed;
    float* h1    = (float*)(fixed + 4096000ull);
    float* wp    = (float*)(fixed + 8192000ull);
    float* hs    = (float*)(fixed + 8192000ull + 266240ull);
    float* cs    = (float*)(fixed + 8192000ull + 266240ull + 8000ull);
    int*   map   = (int*)  (fixed + 8192000ull + 266240ull + 8000ull + 512000ull);

    compose_kernel<<<130, 512, 0, stream>>>(
        ccba_W, ccba_b, cdtx_W, cdtx_b, cust_W, cust_b,
        dp_W, dp_b, remit_W, remit_b, Wih0, bih0, bhh0, wp);

    map_build_kernel<<<dim3(NEVS / 256, 5), 256, 0, stream>>>(
        ccba_bi, ccba_ti, cdtx_bi, cdtx_ti, cust_bi, cust_ti,
        dp_bi, dp_ti, remit_bi, remit_ti, map);

    int first = 1;
    for (int f0 = 0; f0 < TLEN; f0 += tcm) {
        const int len = (TLEN - f0 < tcm) ? (TLEN - f0) : tcm;
        project_kernel<<<dim3(250, 2), 512, 0, stream>>>(
            ccba_num,
            cdtx_num, cdtx_cat, cdtx_tab,
            cust_num, cust_cat, cust_tab,
            dp_num, dp_cat, dp_tab,
            remit_num, remit_cat, remit_tab,
            wp, map, gf, gb, f0, len, tcm);
        rec_chunk_kernel<<<500, 256, 0, stream>>>(
            gf, gb, Whh0, Whr0, h0, hs, cs, f0, len, tcm, first);
        first = 0;
    }

    lstm1_kernel<<<250, 256, 0, stream>>>(h0, Wih1, Whh1, Whr1, bih1, bhh1, h1);
    mean_kernel<<<(BATCH * TLEN + 255) / 256, 256, 0, stream>>>((const float2*)h1, out);
}